// Round 7
// baseline (2105.623 us; speedup 1.0000x reference)
//
#include <hip/hip_runtime.h>

#define B_SZ 1024
#define T_SZ 128
#define HID 512
#define FEAT 128
#define LAB 100

typedef __attribute__((ext_vector_type(8))) short short8;
typedef __attribute__((ext_vector_type(4))) float float4v;
typedef __attribute__((ext_vector_type(8))) __bf16 bf8_t;

// Canonical module-scope scratch (rewritten every call)
__device__ __attribute__((aligned(16))) int            g_x[B_SZ * T_SZ * 2];
__device__ __attribute__((aligned(16))) unsigned short g_len[1500 * 64];
__device__ __attribute__((aligned(16))) unsigned short g_ipd[256 * 64];
__device__ __attribute__((aligned(16))) unsigned short g_wh[HID * HID];
__device__ __attribute__((aligned(16))) unsigned short g_fc2[LAB * HID];
__device__ __attribute__((aligned(16))) float          g_fc2b[LAB];
__device__ __attribute__((aligned(16))) unsigned short g_wch[HID * FEAT];
__device__ __attribute__((aligned(16))) unsigned short g_wcl[HID * FEAT];
__device__ __attribute__((aligned(16))) float          g_btot[HID];

__device__ __forceinline__ float bf2f(unsigned short u) {
    union { unsigned int i; float f; } z; z.i = ((unsigned int)u) << 16; return z.f;
}
__device__ __forceinline__ unsigned short f2bf(float f) {
    union { float f; unsigned int i; } z; z.f = f;
    unsigned int r = z.i + 0x7FFFu + ((z.i >> 16) & 1u);
    return (unsigned short)(r >> 16);
}
__device__ __forceinline__ float4v mfma16(short8 a, short8 b, float4v c) {
    return __builtin_amdgcn_mfma_f32_16x16x32_bf16(
        __builtin_bit_cast(bf8_t, a), __builtin_bit_cast(bf8_t, b), c, 0, 0, 0);
}

// ---- canonicalize x (int64 or int32 -> int32, clamped to [0,255]) ----------
__global__ void conv_x_kernel(const int* __restrict__ xi) {
    __shared__ int is64;
    if (threadIdx.x == 0) {
        int nz = 0;
        for (int j = 1; j < 64; j += 2) nz |= xi[j];   // int64: odd words all 0
        is64 = (nz == 0) ? 1 : 0;
    }
    __syncthreads();
    const int n = B_SZ * T_SZ * 2;
    const int i64 = is64;
    for (int i = blockIdx.x * blockDim.x + threadIdx.x; i < n; i += gridDim.x * blockDim.x) {
        int v = i64 ? xi[2 * i] : xi[i];
        v = v < 0 ? 0 : (v > 255 ? 255 : v);
        g_x[i] = v;
    }
}

// ---- canonicalize float (f32) tensors -> bf16 tables; fc2_b -> f32 ---------
__global__ void conv_floats_kernel(const float* __restrict__ len_e,
                                   const float* __restrict__ ipd_e,
                                   const float* __restrict__ h2h,
                                   const float* __restrict__ fc2,
                                   const float* __restrict__ fc2b) {
    const int N0 = 1500 * 64, N1 = 256 * 64, N2 = HID * HID, N3 = LAB * HID, N4 = LAB;
    const int total = N0 + N1 + N2 + N3 + N4;
    for (int i = blockIdx.x * blockDim.x + threadIdx.x; i < total; i += gridDim.x * blockDim.x) {
        int j = i;
        if (j < N0) { g_len[j] = f2bf(len_e[j]); continue; }
        j -= N0;
        if (j < N1) { g_ipd[j] = f2bf(ipd_e[j]); continue; }
        j -= N1;
        if (j < N2) { g_wh[j] = f2bf(h2h[j]); continue; }
        j -= N2;
        if (j < N3) { g_fc2[j] = f2bf(fc2[j]); continue; }
        j -= N3;
        g_fc2b[j] = fc2b[j];
    }
}

// ---- prep: W_comb = x2h_w @ fc1_w (f32 acc -> bf16 hi/lo), combined bias ---
__global__ void prep_kernel(const float* __restrict__ fc1w, const float* __restrict__ fc1b,
                            const float* __restrict__ x2hw, const float* __restrict__ x2hb,
                            const float* __restrict__ h2hb) {
    int tid = threadIdx.x;
    int nl  = tid >> 5;            // 0..7
    int f0  = (tid & 31) << 2;     // 0..124
    int n   = blockIdx.x * 8 + nl; // 0..511
    float a0 = 0.f, a1 = 0.f, a2 = 0.f, a3 = 0.f;
    for (int k = 0; k < 128; k++) {
        float a = x2hw[n * 128 + k];
        const float* fr = fc1w + k * 128 + f0;
        a0 += a * fr[0]; a1 += a * fr[1]; a2 += a * fr[2]; a3 += a * fr[3];
    }
    float vs[4] = {a0, a1, a2, a3};
    for (int j = 0; j < 4; j++) {
        unsigned short h = f2bf(vs[j]);
        g_wch[n * 128 + f0 + j] = h;
        g_wcl[n * 128 + f0 + j] = f2bf(vs[j] - bf2f(h));
    }
    if ((tid & 31) == 0) {
        float s = 0.f;
        for (int k = 0; k < 128; k++) s += x2hw[n * 128 + k] * fc1b[k];
        g_btot[n] = s + x2hb[n] + h2hb[n];
    }
}

// ---------------------------------------------------------------------------
// Main fused kernel.  One block = 16 batch rows, all 128 timesteps; h in LDS
// (hi/lo bf16, single buffer + 2 barriers/step).  grid 64 x 512.
//   A-frag = W rows : A[row=lane&15 -> hidden n][k=q*8+j]
//   B-frag = h^T    : B[col=lane&15 -> batch m][k=q*8+j]
//   C/D    : row=q*4+r -> hidden n, col=lane&15 -> batch m
// ---------------------------------------------------------------------------
__launch_bounds__(512)
__global__ void rnn_kernel(float* __restrict__ out) {
    constexpr int HP = HID + 8;   // 520
    constexpr int FP = FEAT + 8;  // 136
    __shared__ __attribute__((aligned(16))) unsigned short hT[2][16 * HP];
    __shared__ __attribute__((aligned(16))) unsigned short fT[16 * FP];
    __shared__ int xb[T_SZ * 32];

    const int tid  = threadIdx.x;
    const int wv   = tid >> 6;
    const int ln   = tid & 63;
    const int mcol = ln & 15;
    const int q    = ln >> 4;
    const int b0   = blockIdx.x * 16;
    const int ntg0 = wv * 4;

    for (int i = 0; i < 8; i++) {
        int flat = i * 512 + tid;
        int m = flat >> 8, tc = flat & 255;
        xb[(tc >> 1) * 32 + m * 2 + (tc & 1)] = g_x[(b0 + m) * 256 + tc];
    }
    for (int i = tid; i < 16 * HP; i += 512) { hT[0][i] = 0; hT[1][i] = 0; }

    short8 wc_hi[4][4], wc_lo[4][4];
#pragma unroll
    for (int nt = 0; nt < 4; nt++)
#pragma unroll
        for (int kt = 0; kt < 4; kt++) {
            int off = ((ntg0 + nt) * 16 + mcol) * 128 + kt * 32 + q * 8;
            wc_hi[nt][kt] = *(const short8*)(g_wch + off);
            wc_lo[nt][kt] = *(const short8*)(g_wcl + off);
        }
    float4v bt[4];
#pragma unroll
    for (int nt = 0; nt < 4; nt++)
        bt[nt] = *(const float4v*)(g_btot + (ntg0 + nt) * 16 + q * 4);

    const int gm   = tid >> 5;
    const int gf   = (tid & 31) << 2;
    const int gc   = gf >> 6;
    const unsigned short* gtab = gc ? g_ipd : g_len;
    const int gsub = gf & 63;

    int whoff[4];
#pragma unroll
    for (int nt = 0; nt < 4; nt++) whoff[nt] = ((ntg0 + nt) * 16 + mcol) * 512 + q * 8;
    const int hoff  = mcol * HP + q * 8;
    const int fToff = mcol * FP + q * 8;

    __syncthreads();

    for (int t = 0; t < T_SZ; t++) {
        {
            int idx = xb[t * 32 + gm * 2 + gc];
            uint2 v = *(const uint2*)(gtab + idx * 64 + gsub);
            *(uint2*)&fT[gm * FP + gf] = v;
        }
        __syncthreads();   // (A) fT ready; h writes of t-1 visible

        float4v acc[4];
#pragma unroll
        for (int nt = 0; nt < 4; nt++) acc[nt] = bt[nt];

#pragma unroll
        for (int kt = 0; kt < 4; kt++) {
            short8 bf = *(const short8*)&fT[fToff + kt * 32];
#pragma unroll
            for (int nt = 0; nt < 4; nt++) {
                acc[nt] = mfma16(wc_hi[nt][kt], bf, acc[nt]);
                acc[nt] = mfma16(wc_lo[nt][kt], bf, acc[nt]);
            }
        }
#pragma unroll 4
        for (int kt = 0; kt < 16; kt++) {
            short8 w0 = *(const short8*)(g_wh + whoff[0] + kt * 32);
            short8 w1 = *(const short8*)(g_wh + whoff[1] + kt * 32);
            short8 w2 = *(const short8*)(g_wh + whoff[2] + kt * 32);
            short8 w3 = *(const short8*)(g_wh + whoff[3] + kt * 32);
            short8 bhi = *(const short8*)&hT[0][hoff + kt * 32];
            short8 blo = *(const short8*)&hT[1][hoff + kt * 32];
            acc[0] = mfma16(w0, bhi, acc[0]); acc[0] = mfma16(w0, blo, acc[0]);
            acc[1] = mfma16(w1, bhi, acc[1]); acc[1] = mfma16(w1, blo, acc[1]);
            acc[2] = mfma16(w2, bhi, acc[2]); acc[2] = mfma16(w2, blo, acc[2]);
            acc[3] = mfma16(w3, bhi, acc[3]); acc[3] = mfma16(w3, blo, acc[3]);
        }
        __syncthreads();   // (B) all hT/fT reads of step t done

#pragma unroll
        for (int nt = 0; nt < 4; nt++) {
            unsigned short hi4[4], lo4[4];
#pragma unroll
            for (int r = 0; r < 4; r++) {
                float v = acc[nt][r];
                v = fminf(15.f, fmaxf(-15.f, v));
                float e = __expf(2.0f * v);
                float th = 1.0f - 2.0f / (e + 1.0f);
                unsigned short h16 = f2bf(th);
                hi4[r] = h16;
                lo4[r] = f2bf(th - bf2f(h16));
            }
            int waddr = mcol * HP + (ntg0 + nt) * 16 + q * 4;
            uint2 vh = { (unsigned)hi4[0] | ((unsigned)hi4[1] << 16),
                         (unsigned)hi4[2] | ((unsigned)hi4[3] << 16) };
            uint2 vl = { (unsigned)lo4[0] | ((unsigned)lo4[1] << 16),
                         (unsigned)lo4[2] | ((unsigned)lo4[3] << 16) };
            *(uint2*)&hT[0][waddr] = vh;
            *(uint2*)&hT[1][waddr] = vl;
        }
    }
    __syncthreads();

    // fc2 epilogue: out^T = fc2 * h_last^T  (f32 stores — the actual fix)
    if (wv < 7) {
        float4v a2 = {0.f, 0.f, 0.f, 0.f};
        int lA = wv * 16 + mcol; if (lA > 99) lA = 99;
#pragma unroll 4
        for (int kt = 0; kt < 16; kt++) {
            short8 fa  = *(const short8*)(g_fc2 + lA * 512 + kt * 32 + q * 8);
            short8 bhi = *(const short8*)&hT[0][hoff + kt * 32];
            short8 blo = *(const short8*)&hT[1][hoff + kt * 32];
            a2 = mfma16(fa, bhi, a2);
            a2 = mfma16(fa, blo, a2);
        }
#pragma unroll
        for (int r = 0; r < 4; r++) {
            int l = wv * 16 + q * 4 + r;
            if (l < 100) {
                out[(b0 + mcol) * 100 + l] = a2[r] + g_fc2b[l];
            }
        }
    }
}

extern "C" void kernel_launch(void* const* d_in, const int* in_sizes, int n_in,
                              void* d_out, int out_size, void* d_ws, size_t ws_size,
                              hipStream_t stream) {
    conv_x_kernel<<<256, 256, 0, stream>>>((const int*)d_in[0]);
    conv_floats_kernel<<<1024, 256, 0, stream>>>(
        (const float*)d_in[1], (const float*)d_in[2], (const float*)d_in[7],
        (const float*)d_in[9], (const float*)d_in[10]);
    prep_kernel<<<64, 256, 0, stream>>>(
        (const float*)d_in[3], (const float*)d_in[4], (const float*)d_in[5],
        (const float*)d_in[6], (const float*)d_in[8]);
    rnn_kernel<<<64, 512, 0, stream>>>((float*)d_out);
}

// Round 8
// 2018.646 us; speedup vs baseline: 1.0431x; 1.0431x over previous
//
#include <hip/hip_runtime.h>

#define B_SZ 1024
#define T_SZ 128
#define HID 512
#define FEAT 128
#define LAB 100

// ---- d_ws layout (byte offsets, all 16B-aligned) ----
#define OFF_X     0u          // int[262144]      1 MB
#define OFF_WH    1048576u    // ushort[262144]   512 KB
#define OFF_LEN   1572864u    // ushort[96000]
#define OFF_IPD   1764864u    // ushort[16384]
#define OFF_FC2   1797632u    // ushort[51200]
#define OFF_WCH   1900032u    // ushort[65536]
#define OFF_WCL   2031104u    // ushort[65536]
#define OFF_BTOT  2162176u    // float[512]
#define OFF_FC2B  2164224u    // float[100]
#define WS_NEED   2164624u

typedef __attribute__((ext_vector_type(8))) short short8;
typedef __attribute__((ext_vector_type(4))) float float4v;
typedef __attribute__((ext_vector_type(8))) __bf16 bf8_t;

// fallback scratch if ws_size too small (module-global path is slow but correct)
__device__ __attribute__((aligned(16))) unsigned char g_blob[WS_NEED];

__device__ __forceinline__ float bf2f(unsigned short u) {
    union { unsigned int i; float f; } z; z.i = ((unsigned int)u) << 16; return z.f;
}
__device__ __forceinline__ unsigned short f2bf(float f) {
    union { float f; unsigned int i; } z; z.f = f;
    unsigned int r = z.i + 0x7FFFu + ((z.i >> 16) & 1u);
    return (unsigned short)(r >> 16);
}
__device__ __forceinline__ float4v mfma16(short8 a, short8 b, float4v c) {
    return __builtin_amdgcn_mfma_f32_16x16x32_bf16(
        __builtin_bit_cast(bf8_t, a), __builtin_bit_cast(bf8_t, b), c, 0, 0, 0);
}

// ---- canonicalize x (int64 or int32 -> int32, clamped to [0,255]) ----------
__global__ void conv_x_kernel(const int* __restrict__ xi, int* __restrict__ xo) {
    __shared__ int is64;
    if (threadIdx.x == 0) {
        int nz = 0;
        for (int j = 1; j < 64; j += 2) nz |= xi[j];   // int64: odd words all 0
        is64 = (nz == 0) ? 1 : 0;
    }
    __syncthreads();
    const int n = B_SZ * T_SZ * 2;
    const int i64 = is64;
    for (int i = blockIdx.x * blockDim.x + threadIdx.x; i < n; i += gridDim.x * blockDim.x) {
        int v = i64 ? xi[2 * i] : xi[i];
        v = v < 0 ? 0 : (v > 255 ? 255 : v);
        xo[i] = v;
    }
}

// ---- canonicalize f32 tensors -> bf16 tables in ws; fc2_b -> f32 -----------
__global__ void conv_floats_kernel(const float* __restrict__ len_e,
                                   const float* __restrict__ ipd_e,
                                   const float* __restrict__ h2h,
                                   const float* __restrict__ fc2,
                                   const float* __restrict__ fc2b,
                                   unsigned short* __restrict__ o_len,
                                   unsigned short* __restrict__ o_ipd,
                                   unsigned short* __restrict__ o_wh,
                                   unsigned short* __restrict__ o_fc2,
                                   float* __restrict__ o_fc2b) {
    const int N0 = 1500 * 64, N1 = 256 * 64, N2 = HID * HID, N3 = LAB * HID, N4 = LAB;
    const int total = N0 + N1 + N2 + N3 + N4;
    for (int i = blockIdx.x * blockDim.x + threadIdx.x; i < total; i += gridDim.x * blockDim.x) {
        int j = i;
        if (j < N0) { o_len[j] = f2bf(len_e[j]); continue; }
        j -= N0;
        if (j < N1) { o_ipd[j] = f2bf(ipd_e[j]); continue; }
        j -= N1;
        if (j < N2) { o_wh[j] = f2bf(h2h[j]); continue; }
        j -= N2;
        if (j < N3) { o_fc2[j] = f2bf(fc2[j]); continue; }
        j -= N3;
        o_fc2b[j] = fc2b[j];
    }
}

// ---- prep: W_comb = x2h_w @ fc1_w (f32 acc -> bf16 hi/lo), combined bias ---
__global__ void prep_kernel(const float* __restrict__ fc1w, const float* __restrict__ fc1b,
                            const float* __restrict__ x2hw, const float* __restrict__ x2hb,
                            const float* __restrict__ h2hb,
                            unsigned short* __restrict__ o_wch,
                            unsigned short* __restrict__ o_wcl,
                            float* __restrict__ o_btot) {
    int tid = threadIdx.x;
    int nl  = tid >> 5;
    int f0  = (tid & 31) << 2;
    int n   = blockIdx.x * 8 + nl;
    float a0 = 0.f, a1 = 0.f, a2 = 0.f, a3 = 0.f;
    for (int k = 0; k < 128; k++) {
        float a = x2hw[n * 128 + k];
        const float* fr = fc1w + k * 128 + f0;
        a0 += a * fr[0]; a1 += a * fr[1]; a2 += a * fr[2]; a3 += a * fr[3];
    }
    float vs[4] = {a0, a1, a2, a3};
    for (int j = 0; j < 4; j++) {
        unsigned short h = f2bf(vs[j]);
        o_wch[n * 128 + f0 + j] = h;
        o_wcl[n * 128 + f0 + j] = f2bf(vs[j] - bf2f(h));
    }
    if ((tid & 31) == 0) {
        float s = 0.f;
        for (int k = 0; k < 128; k++) s += x2hw[n * 128 + k] * fc1b[k];
        o_btot[n] = s + x2hb[n] + h2hb[n];
    }
}

// ---------------------------------------------------------------------------
// Main fused kernel.  grid 64 x 1024: block = 16 batch rows, 16 waves, each
// wave owns 2 n-tiles (32 hidden outputs).  h in LDS (hi/lo bf16, single
// buffer + 2 barriers/step).  All tables read from d_ws (hipMalloc'd).
//   A-frag = W rows : A[row=lane&15 -> hidden n][k=q*8+j]
//   B-frag = h^T    : B[col=lane&15 -> batch m][k=q*8+j]
//   C/D    : row=q*4+r -> hidden n, col=lane&15 -> batch m
// ---------------------------------------------------------------------------
__launch_bounds__(1024)
__global__ void rnn_kernel(const int* __restrict__ xw,
                           const unsigned short* __restrict__ lenw,
                           const unsigned short* __restrict__ ipdw,
                           const unsigned short* __restrict__ whw,
                           const unsigned short* __restrict__ fc2w,
                           const float* __restrict__ fc2bw,
                           const unsigned short* __restrict__ wchw,
                           const unsigned short* __restrict__ wclw,
                           const float* __restrict__ btotw,
                           float* __restrict__ out) {
    constexpr int HP = HID + 8;   // 520
    constexpr int FP = FEAT + 8;  // 136
    __shared__ __attribute__((aligned(16))) unsigned short hT[2][16 * HP];
    __shared__ __attribute__((aligned(16))) unsigned short fT[16 * FP];
    __shared__ int xb[T_SZ * 32];

    const int tid  = threadIdx.x;
    const int wv   = tid >> 6;     // 0..15
    const int ln   = tid & 63;
    const int mcol = ln & 15;
    const int q    = ln >> 4;
    const int b0   = blockIdx.x * 16;
    const int ntg0 = wv * 2;       // 2 n-tiles per wave

    for (int i = 0; i < 4; i++) {
        int flat = i * 1024 + tid;          // 0..4095
        int m = flat >> 8, tc = flat & 255;
        xb[(tc >> 1) * 32 + m * 2 + (tc & 1)] = xw[(b0 + m) * 256 + tc];
    }
    for (int i = tid; i < 16 * HP; i += 1024) { hT[0][i] = 0; hT[1][i] = 0; }

    short8 wc_hi[2][4], wc_lo[2][4];
#pragma unroll
    for (int nt = 0; nt < 2; nt++)
#pragma unroll
        for (int kt = 0; kt < 4; kt++) {
            int off = ((ntg0 + nt) * 16 + mcol) * 128 + kt * 32 + q * 8;
            wc_hi[nt][kt] = *(const short8*)(wchw + off);
            wc_lo[nt][kt] = *(const short8*)(wclw + off);
        }
    float4v bt[2];
#pragma unroll
    for (int nt = 0; nt < 2; nt++)
        bt[nt] = *(const float4v*)(btotw + (ntg0 + nt) * 16 + q * 4);

    // gather roles: first 512 threads, (batch row gm, 4 feature elems)
    const int gm   = (tid >> 5) & 15;
    const int gf   = (tid & 31) << 2;
    const int gc   = gf >> 6;
    const unsigned short* gtab = gc ? ipdw : lenw;
    const int gsub = gf & 63;
    const bool gact = (tid < 512);

    int whoff[2];
#pragma unroll
    for (int nt = 0; nt < 2; nt++) whoff[nt] = ((ntg0 + nt) * 16 + mcol) * 512 + q * 8;
    const int hoff  = mcol * HP + q * 8;
    const int fToff = mcol * FP + q * 8;

    __syncthreads();

    for (int t = 0; t < T_SZ; t++) {
        if (gact) {
            int idx = xb[t * 32 + gm * 2 + gc];
            uint2 v = *(const uint2*)(gtab + idx * 64 + gsub);
            *(uint2*)&fT[gm * FP + gf] = v;
        }
        __syncthreads();   // (A) fT ready; h writes of t-1 visible

        float4v acc[2];
#pragma unroll
        for (int nt = 0; nt < 2; nt++) acc[nt] = bt[nt];

        // feats @ Wc^T (hi + lo)
#pragma unroll
        for (int kt = 0; kt < 4; kt++) {
            short8 bf = *(const short8*)&fT[fToff + kt * 32];
#pragma unroll
            for (int nt = 0; nt < 2; nt++) {
                acc[nt] = mfma16(wc_hi[nt][kt], bf, acc[nt]);
                acc[nt] = mfma16(wc_lo[nt][kt], bf, acc[nt]);
            }
        }
        // h @ Wh^T (W streamed via L2, h hi/lo from LDS)
#pragma unroll 4
        for (int kt = 0; kt < 16; kt++) {
            short8 w0 = *(const short8*)(whw + whoff[0] + kt * 32);
            short8 w1 = *(const short8*)(whw + whoff[1] + kt * 32);
            short8 bhi = *(const short8*)&hT[0][hoff + kt * 32];
            short8 blo = *(const short8*)&hT[1][hoff + kt * 32];
            acc[0] = mfma16(w0, bhi, acc[0]); acc[0] = mfma16(w0, blo, acc[0]);
            acc[1] = mfma16(w1, bhi, acc[1]); acc[1] = mfma16(w1, blo, acc[1]);
        }
        __syncthreads();   // (B) all hT/fT reads of step t done

#pragma unroll
        for (int nt = 0; nt < 2; nt++) {
            unsigned short hi4[4], lo4[4];
#pragma unroll
            for (int r = 0; r < 4; r++) {
                float v = acc[nt][r];
                v = fminf(15.f, fmaxf(-15.f, v));
                float e = __expf(2.0f * v);
                float th = 1.0f - 2.0f / (e + 1.0f);
                unsigned short h16 = f2bf(th);
                hi4[r] = h16;
                lo4[r] = f2bf(th - bf2f(h16));
            }
            int waddr = mcol * HP + (ntg0 + nt) * 16 + q * 4;
            uint2 vh = { (unsigned)hi4[0] | ((unsigned)hi4[1] << 16),
                         (unsigned)hi4[2] | ((unsigned)hi4[3] << 16) };
            uint2 vl = { (unsigned)lo4[0] | ((unsigned)lo4[1] << 16),
                         (unsigned)lo4[2] | ((unsigned)lo4[3] << 16) };
            *(uint2*)&hT[0][waddr] = vh;
            *(uint2*)&hT[1][waddr] = vl;
        }
    }
    __syncthreads();

    // fc2 epilogue: out^T = fc2 * h_last^T (waves 0..6 cover 112 >= 100 labels)
    if (wv < 7) {
        float4v a2 = {0.f, 0.f, 0.f, 0.f};
        int lA = wv * 16 + mcol; if (lA > 99) lA = 99;
#pragma unroll 4
        for (int kt = 0; kt < 16; kt++) {
            short8 fa  = *(const short8*)(fc2w + lA * 512 + kt * 32 + q * 8);
            short8 bhi = *(const short8*)&hT[0][hoff + kt * 32];
            short8 blo = *(const short8*)&hT[1][hoff + kt * 32];
            a2 = mfma16(fa, bhi, a2);
            a2 = mfma16(fa, blo, a2);
        }
#pragma unroll
        for (int r = 0; r < 4; r++) {
            int l = wv * 16 + q * 4 + r;
            if (l < 100) {
                out[(b0 + mcol) * 100 + l] = a2[r] + fc2bw[l];
            }
        }
    }
}

extern "C" void kernel_launch(void* const* d_in, const int* in_sizes, int n_in,
                              void* d_out, int out_size, void* d_ws, size_t ws_size,
                              hipStream_t stream) {
    unsigned char* base = (unsigned char*)d_ws;
    if (ws_size < (size_t)WS_NEED) {
        void* p = nullptr;
        hipGetSymbolAddress(&p, HIP_SYMBOL(g_blob));   // address query only; capture-safe
        base = (unsigned char*)p;
    }
    int*            w_x    = (int*)(base + OFF_X);
    unsigned short* w_wh   = (unsigned short*)(base + OFF_WH);
    unsigned short* w_len  = (unsigned short*)(base + OFF_LEN);
    unsigned short* w_ipd  = (unsigned short*)(base + OFF_IPD);
    unsigned short* w_fc2  = (unsigned short*)(base + OFF_FC2);
    unsigned short* w_wch  = (unsigned short*)(base + OFF_WCH);
    unsigned short* w_wcl  = (unsigned short*)(base + OFF_WCL);
    float*          w_btot = (float*)(base + OFF_BTOT);
    float*          w_fc2b = (float*)(base + OFF_FC2B);

    conv_x_kernel<<<256, 256, 0, stream>>>((const int*)d_in[0], w_x);
    conv_floats_kernel<<<1024, 256, 0, stream>>>(
        (const float*)d_in[1], (const float*)d_in[2], (const float*)d_in[7],
        (const float*)d_in[9], (const float*)d_in[10],
        w_len, w_ipd, w_wh, w_fc2, w_fc2b);
    prep_kernel<<<64, 256, 0, stream>>>(
        (const float*)d_in[3], (const float*)d_in[4], (const float*)d_in[5],
        (const float*)d_in[6], (const float*)d_in[8],
        w_wch, w_wcl, w_btot);
    rnn_kernel<<<64, 1024, 0, stream>>>(
        w_x, w_len, w_ipd, w_wh, w_fc2, w_fc2b, w_wch, w_wcl, w_btot,
        (float*)d_out);
}

// Round 9
// 1451.430 us; speedup vs baseline: 1.4507x; 1.3908x over previous
//
#include <hip/hip_runtime.h>

#define B_SZ 1024
#define T_SZ 128
#define HID 512
#define FEAT 128
#define LAB 100
#define NS 4
#define SLICE 128

// ---- d_ws layout (byte offsets, 16B-aligned) ----
#define OFF_X     0u          // int[262144]
#define OFF_WH    1048576u    // ushort[512*512]
#define OFF_LEN   1572864u    // ushort[96000]
#define OFF_IPD   1764864u    // ushort[16384]
#define OFF_FC2   1797632u    // ushort[51200]
#define OFF_WCH   1900032u    // ushort[65536]
#define OFF_WCL   2031104u    // ushort[65536]
#define OFF_BTOT  2162176u    // float[512]
#define OFF_FC2B  2164224u    // float[100] (+pad)
#define OFF_HBUF  2164736u    // ushort[64][2][4][2][16][128] = 4 MB
#define OFF_FLAG  6359040u    // int[64*4] (+pad)
#define WS_NEED   6360064u

typedef __attribute__((ext_vector_type(8))) short short8;
typedef __attribute__((ext_vector_type(4))) float float4v;
typedef __attribute__((ext_vector_type(8))) __bf16 bf8_t;
typedef unsigned long long ull;

__device__ __attribute__((aligned(16))) unsigned char g_blob[WS_NEED]; // fallback only

__device__ __forceinline__ float bf2f(unsigned short u) {
    union { unsigned int i; float f; } z; z.i = ((unsigned int)u) << 16; return z.f;
}
__device__ __forceinline__ unsigned short f2bf(float f) {
    union { float f; unsigned int i; } z; z.f = f;
    unsigned int r = z.i + 0x7FFFu + ((z.i >> 16) & 1u);
    return (unsigned short)(r >> 16);
}
__device__ __forceinline__ float4v mfma16(short8 a, short8 b, float4v c) {
    return __builtin_amdgcn_mfma_f32_16x16x32_bf16(
        __builtin_bit_cast(bf8_t, a), __builtin_bit_cast(bf8_t, b), c, 0, 0, 0);
}
// LDS layouts, XOR-chunk swizzled (16B chunks) for bank uniformity
__device__ __forceinline__ int h_addr(int p, int m, int k) {
    return p * 8192 + m * 512 + ((((k >> 3)) ^ m) & 63) * 8 + (k & 7);
}
__device__ __forceinline__ int wh_addr(int r, int k) {
    return r * 512 + ((((k >> 3)) ^ (r & 63)) & 63) * 8 + (k & 7);
}
#define HB_IDX(g, par, sp, pl, m, nl) \
    (((((((g) * 2 + (par)) * 4 + (sp)) * 2 + (pl)) * 16 + (m)) * 128) + (nl))

// ---- zero the sync flags (every call, before rnn) ----
__global__ void zero_flags_kernel(int* __restrict__ flags) {
    flags[threadIdx.x] = 0;
}

// ---- canonicalize x ----
__global__ void conv_x_kernel(const int* __restrict__ xi, int* __restrict__ xo) {
    __shared__ int is64;
    if (threadIdx.x == 0) {
        int nz = 0;
        for (int j = 1; j < 64; j += 2) nz |= xi[j];
        is64 = (nz == 0) ? 1 : 0;
    }
    __syncthreads();
    const int n = B_SZ * T_SZ * 2;
    const int i64 = is64;
    for (int i = blockIdx.x * blockDim.x + threadIdx.x; i < n; i += gridDim.x * blockDim.x) {
        int v = i64 ? xi[2 * i] : xi[i];
        v = v < 0 ? 0 : (v > 255 ? 255 : v);
        xo[i] = v;
    }
}

// ---- canonicalize f32 tensors -> bf16 tables ----
__global__ void conv_floats_kernel(const float* __restrict__ len_e, const float* __restrict__ ipd_e,
                                   const float* __restrict__ h2h, const float* __restrict__ fc2,
                                   const float* __restrict__ fc2b,
                                   unsigned short* __restrict__ o_len, unsigned short* __restrict__ o_ipd,
                                   unsigned short* __restrict__ o_wh, unsigned short* __restrict__ o_fc2,
                                   float* __restrict__ o_fc2b) {
    const int N0 = 1500 * 64, N1 = 256 * 64, N2 = HID * HID, N3 = LAB * HID, N4 = LAB;
    const int total = N0 + N1 + N2 + N3 + N4;
    for (int i = blockIdx.x * blockDim.x + threadIdx.x; i < total; i += gridDim.x * blockDim.x) {
        int j = i;
        if (j < N0) { o_len[j] = f2bf(len_e[j]); continue; }
        j -= N0;
        if (j < N1) { o_ipd[j] = f2bf(ipd_e[j]); continue; }
        j -= N1;
        if (j < N2) { o_wh[j] = f2bf(h2h[j]); continue; }
        j -= N2;
        if (j < N3) { o_fc2[j] = f2bf(fc2[j]); continue; }
        j -= N3;
        o_fc2b[j] = fc2b[j];
    }
}

// ---- prep: W_comb = x2h_w @ fc1_w (bf16 hi/lo) + combined bias ----
__global__ void prep_kernel(const float* __restrict__ fc1w, const float* __restrict__ fc1b,
                            const float* __restrict__ x2hw, const float* __restrict__ x2hb,
                            const float* __restrict__ h2hb,
                            unsigned short* __restrict__ o_wch, unsigned short* __restrict__ o_wcl,
                            float* __restrict__ o_btot) {
    int tid = threadIdx.x;
    int nl  = tid >> 5;
    int f0  = (tid & 31) << 2;
    int n   = blockIdx.x * 8 + nl;
    float a0 = 0.f, a1 = 0.f, a2 = 0.f, a3 = 0.f;
    for (int k = 0; k < 128; k++) {
        float a = x2hw[n * 128 + k];
        const float* fr = fc1w + k * 128 + f0;
        a0 += a * fr[0]; a1 += a * fr[1]; a2 += a * fr[2]; a3 += a * fr[3];
    }
    float vs[4] = {a0, a1, a2, a3};
    for (int j = 0; j < 4; j++) {
        unsigned short h = f2bf(vs[j]);
        o_wch[n * 128 + f0 + j] = h;
        o_wcl[n * 128 + f0 + j] = f2bf(vs[j] - bf2f(h));
    }
    if ((tid & 31) == 0) {
        float s = 0.f;
        for (int k = 0; k < 128; k++) s += x2hw[n * 128 + k] * fc1b[k];
        o_btot[n] = s + x2hb[n] + h2hb[n];
    }
}

// ---------------------------------------------------------------------------
// Persistent RNN: 256 blocks (64 groups x 4 hidden slices) x 256 threads.
// Wh slice (128x512 bf16, 128KB) LDS-resident; h (16x512 hi/lo, 32KB) in LDS.
// Per step: exchange 4KB h-slices via global Hbuf (double-buffered, monotonic
// flags, agent-scope atomics), MFMA from LDS.
// ---------------------------------------------------------------------------
__launch_bounds__(256, 1)
__global__ void rnn_kernel(const int* __restrict__ w_x,
                           const unsigned short* __restrict__ w_len,
                           const unsigned short* __restrict__ w_ipd,
                           const unsigned short* __restrict__ w_wh,
                           const unsigned short* __restrict__ w_fc2,
                           const float* __restrict__ w_fc2b,
                           const unsigned short* __restrict__ w_wch,
                           const unsigned short* __restrict__ w_wcl,
                           const float* __restrict__ w_btot,
                           unsigned short* __restrict__ hb,
                           int* __restrict__ flags,
                           float* __restrict__ out) {
    extern __shared__ unsigned short smem[];
    unsigned short* sWh = smem;            // 65536 ushorts (128 KB)
    unsigned short* sH  = smem + 65536;    // 16384 ushorts (32 KB): [plane][m][k]

    const int tid  = threadIdx.x;
    const int wv   = tid >> 6;             // 0..3
    const int ln   = tid & 63;
    const int mcol = ln & 15;
    const int q    = ln >> 4;
    const int g    = blockIdx.x >> 2;
    const int s    = blockIdx.x & 3;
    const int b0   = g * 16;
    const int jt0  = 2 * wv, jt1 = 2 * wv + 1;   // n-tiles owned by this wave
    ull* hb64 = (ull*)hb;

    // ---- load Wh slice into LDS (swizzled) ----
    for (int it = 0; it < 32; it++) {
        int idx = it * 256 + tid;            // 16B chunk id
        int r = idx >> 6, c = idx & 63;
        uint4 v = *(const uint4*)(w_wh + ((s * SLICE + r) << 9) + (c << 3));
        *(uint4*)&sWh[(r << 9) + (((c ^ (r & 63)) & 63) << 3)] = v;
    }
    // ---- zero h ----
    for (int i = 0; i < 8; i++) {
        uint4 z = {0, 0, 0, 0};
        *(uint4*)&sH[(i * 256 + tid) * 8] = z;
    }
    // ---- persistent Wc fragments + bias ----
    short8 wc_hi[2][4], wc_lo[2][4];
#pragma unroll
    for (int j = 0; j < 2; j++)
#pragma unroll
        for (int kt = 0; kt < 4; kt++) {
            int off = ((s * SLICE + (jt0 + j) * 16 + mcol) * 128) + kt * 32 + q * 8;
            wc_hi[j][kt] = *(const short8*)(w_wch + off);
            wc_lo[j][kt] = *(const short8*)(w_wcl + off);
        }
    float4v bt0 = *(const float4v*)(w_btot + s * SLICE + jt0 * 16 + q * 4);
    float4v bt1 = *(const float4v*)(w_btot + s * SLICE + jt1 * 16 + q * 4);

    __syncthreads();

    for (int t = 0; t < T_SZ; t++) {
        // ---- feats B-frags straight to registers (overlap with spin) ----
        short8 ff[4];
        {
            int xoff = (b0 + mcol) * 256 + t * 2;
            int i0 = w_x[xoff], i1 = w_x[xoff + 1];
            const unsigned short* lr = w_len + i0 * 64 + q * 8;
            const unsigned short* ir = w_ipd + i1 * 64 + q * 8;
            ff[0] = *(const short8*)lr;  ff[1] = *(const short8*)(lr + 32);
            ff[2] = *(const short8*)ir;  ff[3] = *(const short8*)(ir + 32);
        }
        // ---- exchange-in: wait siblings' h_t, copy into sH ----
        if (t >= 1) {
            if (tid < 3) {
                int so = (s + 1 + tid) & 3;
                while (__hip_atomic_load(&flags[g * 4 + so], __ATOMIC_ACQUIRE,
                                         __HIP_MEMORY_SCOPE_AGENT) < t)
                    __builtin_amdgcn_s_sleep(2);
            }
            __syncthreads();
            const int par = t & 1;
#pragma unroll
            for (int i = 0; i < 12; i++) {
                int u   = i * 256 + tid;
                int sp  = (s + 1 + (u >> 10)) & 3;
                int pl  = (u >> 9) & 1;
                int m   = (u >> 5) & 15;
                int nl  = (u & 31) * 4;
                ull v = __hip_atomic_load(hb64 + (HB_IDX(g, par, sp, pl, m, nl) >> 2),
                                          __ATOMIC_RELAXED, __HIP_MEMORY_SCOPE_AGENT);
                union { ull u8; uint2 v2; } cv; cv.u8 = v;
                *(uint2*)&sH[h_addr(pl, m, sp * SLICE + nl)] = cv.v2;
            }
        }
        __syncthreads();   // (A)

        // ---- MFMA ----
        float4v acc0 = bt0, acc1 = bt1;
#pragma unroll
        for (int kt = 0; kt < 4; kt++) {
            acc0 = mfma16(wc_hi[0][kt], ff[kt], acc0);
            acc0 = mfma16(wc_lo[0][kt], ff[kt], acc0);
            acc1 = mfma16(wc_hi[1][kt], ff[kt], acc1);
            acc1 = mfma16(wc_lo[1][kt], ff[kt], acc1);
        }
#pragma unroll 4
        for (int kt = 0; kt < 16; kt++) {
            int k = kt * 32 + q * 8;
            short8 bhi = *(const short8*)&sH[h_addr(0, mcol, k)];
            short8 blo = *(const short8*)&sH[h_addr(1, mcol, k)];
            short8 a0  = *(const short8*)&sWh[wh_addr(jt0 * 16 + mcol, k)];
            short8 a1  = *(const short8*)&sWh[wh_addr(jt1 * 16 + mcol, k)];
            acc0 = mfma16(a0, bhi, acc0); acc0 = mfma16(a0, blo, acc0);
            acc1 = mfma16(a1, bhi, acc1); acc1 = mfma16(a1, blo, acc1);
        }
        __syncthreads();   // (B)

        // ---- tanh -> hi/lo; write own slice to sH + Hbuf ----
        const int wpar = (t + 1) & 1;
#pragma unroll
        for (int j = 0; j < 2; j++) {
            float4v a = j ? acc1 : acc0;
            unsigned short hi4[4], lo4[4];
#pragma unroll
            for (int r = 0; r < 4; r++) {
                float v = fminf(15.f, fmaxf(-15.f, a[r]));
                float e = __expf(2.0f * v);
                float th = 1.0f - 2.0f / (e + 1.0f);
                hi4[r] = f2bf(th);
                lo4[r] = f2bf(th - bf2f(hi4[r]));
            }
            int nl = (j ? jt1 : jt0) * 16 + q * 4;
            union { ull u8; uint2 v2; } vh, vl;
            vh.u8 = (ull)hi4[0] | ((ull)hi4[1] << 16) | ((ull)hi4[2] << 32) | ((ull)hi4[3] << 48);
            vl.u8 = (ull)lo4[0] | ((ull)lo4[1] << 16) | ((ull)lo4[2] << 32) | ((ull)lo4[3] << 48);
            *(uint2*)&sH[h_addr(0, mcol, s * SLICE + nl)] = vh.v2;
            *(uint2*)&sH[h_addr(1, mcol, s * SLICE + nl)] = vl.v2;
            __hip_atomic_store(hb64 + (HB_IDX(g, wpar, s, 0, mcol, nl) >> 2), vh.u8,
                               __ATOMIC_RELAXED, __HIP_MEMORY_SCOPE_AGENT);
            __hip_atomic_store(hb64 + (HB_IDX(g, wpar, s, 1, mcol, nl) >> 2), vl.u8,
                               __ATOMIC_RELAXED, __HIP_MEMORY_SCOPE_AGENT);
        }
        __syncthreads();   // (C) — drains all waves' stores (vmcnt(0) pre-barrier)
        if (tid == 0)
            __hip_atomic_store(&flags[g * 4 + s], t + 1, __ATOMIC_RELEASE,
                               __HIP_MEMORY_SCOPE_AGENT);
    }

    if (s != 0) return;

    // ---- final exchange (t=128, parity 0) + fc2 epilogue on slice-0 blocks ----
    if (tid < 3) {
        int so = 1 + tid;
        while (__hip_atomic_load(&flags[g * 4 + so], __ATOMIC_ACQUIRE,
                                 __HIP_MEMORY_SCOPE_AGENT) < T_SZ)
            __builtin_amdgcn_s_sleep(2);
    }
    __syncthreads();
#pragma unroll
    for (int i = 0; i < 12; i++) {
        int u  = i * 256 + tid;
        int sp = 1 + (u >> 10);
        int pl = (u >> 9) & 1;
        int m  = (u >> 5) & 15;
        int nl = (u & 31) * 4;
        ull v = __hip_atomic_load(hb64 + (HB_IDX(g, 0, sp, pl, m, nl) >> 2),
                                  __ATOMIC_RELAXED, __HIP_MEMORY_SCOPE_AGENT);
        union { ull u8; uint2 v2; } cv; cv.u8 = v;
        *(uint2*)&sH[h_addr(pl, m, sp * SLICE + nl)] = cv.v2;
    }
    __syncthreads();

#pragma unroll
    for (int j = 0; j < 2; j++) {
        int lt = wv + j * 4;                 // l-tiles 0..7
        int lA = lt * 16 + mcol; if (lA > 99) lA = 99;
        float4v a2 = {0.f, 0.f, 0.f, 0.f};
#pragma unroll 4
        for (int kt = 0; kt < 16; kt++) {
            int k = kt * 32 + q * 8;
            short8 fa  = *(const short8*)(w_fc2 + lA * 512 + k);
            short8 bhi = *(const short8*)&sH[h_addr(0, mcol, k)];
            short8 blo = *(const short8*)&sH[h_addr(1, mcol, k)];
            a2 = mfma16(fa, bhi, a2);
            a2 = mfma16(fa, blo, a2);
        }
#pragma unroll
        for (int r = 0; r < 4; r++) {
            int l = lt * 16 + q * 4 + r;
            if (l < 100) out[(b0 + mcol) * 100 + l] = a2[r] + w_fc2b[l];
        }
    }
}

extern "C" void kernel_launch(void* const* d_in, const int* in_sizes, int n_in,
                              void* d_out, int out_size, void* d_ws, size_t ws_size,
                              hipStream_t stream) {
    unsigned char* base = (unsigned char*)d_ws;
    if (ws_size < (size_t)WS_NEED) {
        void* p = nullptr;
        hipGetSymbolAddress(&p, HIP_SYMBOL(g_blob));
        base = (unsigned char*)p;
    }
    int*            w_x    = (int*)(base + OFF_X);
    unsigned short* w_wh   = (unsigned short*)(base + OFF_WH);
    unsigned short* w_len  = (unsigned short*)(base + OFF_LEN);
    unsigned short* w_ipd  = (unsigned short*)(base + OFF_IPD);
    unsigned short* w_fc2  = (unsigned short*)(base + OFF_FC2);
    unsigned short* w_wch  = (unsigned short*)(base + OFF_WCH);
    unsigned short* w_wcl  = (unsigned short*)(base + OFF_WCL);
    float*          w_btot = (float*)(base + OFF_BTOT);
    float*          w_fc2b = (float*)(base + OFF_FC2B);
    unsigned short* w_hbuf = (unsigned short*)(base + OFF_HBUF);
    int*            w_flag = (int*)(base + OFF_FLAG);

    static bool attr_set = false;
    if (!attr_set) {
        hipFuncSetAttribute((const void*)rnn_kernel,
                            hipFuncAttributeMaxDynamicSharedMemorySize, 163840);
        attr_set = true;
    }

    zero_flags_kernel<<<1, 256, 0, stream>>>(w_flag);
    conv_x_kernel<<<256, 256, 0, stream>>>((const int*)d_in[0], w_x);
    conv_floats_kernel<<<1024, 256, 0, stream>>>(
        (const float*)d_in[1], (const float*)d_in[2], (const float*)d_in[7],
        (const float*)d_in[9], (const float*)d_in[10],
        w_len, w_ipd, w_wh, w_fc2, w_fc2b);
    prep_kernel<<<64, 256, 0, stream>>>(
        (const float*)d_in[3], (const float*)d_in[4], (const float*)d_in[5],
        (const float*)d_in[6], (const float*)d_in[8],
        w_wch, w_wcl, w_btot);
    rnn_kernel<<<256, 256, 163840, stream>>>(
        w_x, w_len, w_ipd, w_wh, w_fc2, w_fc2b, w_wch, w_wcl, w_btot,
        w_hbuf, w_flag, (float*)d_out);
}

// Round 12
// 1083.078 us; speedup vs baseline: 1.9441x; 1.3401x over previous
//
#include <hip/hip_runtime.h>

#define B_SZ 1024
#define T_SZ 128
#define HID 512
#define FEAT 128
#define LAB 100
#define SLICE 128

// ---- d_ws layout (byte offsets, 16B-aligned) ----
#define OFF_X     0u          // int[262144]
#define OFF_WH    1048576u    // ushort[512*512]
#define OFF_LEN   1572864u    // ushort[96000]
#define OFF_IPD   1764864u    // ushort[16384]
#define OFF_FC2   1797632u    // ushort[51200]
#define OFF_WCH   1900032u    // ushort[65536]
#define OFF_WCL   2031104u    // ushort[65536]
#define OFF_BTOT  2162176u    // float[512]
#define OFF_FC2B  2164224u    // float[100] (+pad)
#define OFF_HBUF  2164736u    // ushort[4M/2] = 4 MB exchange buffer
#define OFF_SYNC  6359040u    // int[8192] flags, 128B-padded
#define WS_NEED   6391808u

typedef __attribute__((ext_vector_type(8))) short short8;
typedef __attribute__((ext_vector_type(4))) float float4v;
typedef __attribute__((ext_vector_type(8))) __bf16 bf8_t;
typedef unsigned long long ull;

__device__ __attribute__((aligned(16))) unsigned char g_blob[WS_NEED]; // fallback only

__device__ __forceinline__ float bf2f(unsigned short u) {
    union { unsigned int i; float f; } z; z.i = ((unsigned int)u) << 16; return z.f;
}
__device__ __forceinline__ unsigned short f2bf(float f) {
    union { float f; unsigned int i; } z; z.f = f;
    unsigned int r = z.i + 0x7FFFu + ((z.i >> 16) & 1u);
    return (unsigned short)(r >> 16);
}
__device__ __forceinline__ float4v mfma16(short8 a, short8 b, float4v c) {
    return __builtin_amdgcn_mfma_f32_16x16x32_bf16(
        __builtin_bit_cast(bf8_t, a), __builtin_bit_cast(bf8_t, b), c, 0, 0, 0);
}
// LDS layouts, XOR-chunk swizzled (16B chunks)
__device__ __forceinline__ int h_addr(int p, int m, int k) {
    return p * 8192 + m * 512 + ((((k >> 3)) ^ m) & 63) * 8 + (k & 7);
}
__device__ __forceinline__ int wh_addr(int r, int k) {
    return r * 512 + ((((k >> 3)) ^ (r & 63)) & 63) * 8 + (k & 7);
}
// Hbuf layout in WRITER-LANE order: per (g,par,sp,pl,wv) a contiguous 512B
// run of 64 lanes x 8B. Coalesced writes AND reads. ushort index:
#define HB2(g, par, sp, pl, wv, ln) \
    ((((((((g) * 2 + (par)) * 4 + (sp)) * 2 + (pl)) * 8 + (wv)) * 64) + (ln)) * 4)
// flag slot: one 128B line per flag
#define FSLOT(g, s) (((g) * 4 + (s)) * 32)

__global__ void init_sync_kernel(int* __restrict__ sy) {
    for (int i = threadIdx.x; i < 8192; i += 1024) sy[i] = 0;
}

__global__ void conv_x_kernel(const int* __restrict__ xi, int* __restrict__ xo) {
    __shared__ int is64;
    if (threadIdx.x == 0) {
        int nz = 0;
        for (int j = 1; j < 64; j += 2) nz |= xi[j];
        is64 = (nz == 0) ? 1 : 0;
    }
    __syncthreads();
    const int n = B_SZ * T_SZ * 2;
    const int i64 = is64;
    for (int i = blockIdx.x * blockDim.x + threadIdx.x; i < n; i += gridDim.x * blockDim.x) {
        int v = i64 ? xi[2 * i] : xi[i];
        v = v < 0 ? 0 : (v > 255 ? 255 : v);
        xo[i] = v;
    }
}

__global__ void conv_floats_kernel(const float* __restrict__ len_e, const float* __restrict__ ipd_e,
                                   const float* __restrict__ h2h, const float* __restrict__ fc2,
                                   const float* __restrict__ fc2b,
                                   unsigned short* __restrict__ o_len, unsigned short* __restrict__ o_ipd,
                                   unsigned short* __restrict__ o_wh, unsigned short* __restrict__ o_fc2,
                                   float* __restrict__ o_fc2b) {
    const int N0 = 1500 * 64, N1 = 256 * 64, N2 = HID * HID, N3 = LAB * HID, N4 = LAB;
    const int total = N0 + N1 + N2 + N3 + N4;
    for (int i = blockIdx.x * blockDim.x + threadIdx.x; i < total; i += gridDim.x * blockDim.x) {
        int j = i;
        if (j < N0) { o_len[j] = f2bf(len_e[j]); continue; }
        j -= N0;
        if (j < N1) { o_ipd[j] = f2bf(ipd_e[j]); continue; }
        j -= N1;
        if (j < N2) { o_wh[j] = f2bf(h2h[j]); continue; }
        j -= N2;
        if (j < N3) { o_fc2[j] = f2bf(fc2[j]); continue; }
        j -= N3;
        o_fc2b[j] = fc2b[j];
    }
}

__global__ void prep_kernel(const float* __restrict__ fc1w, const float* __restrict__ fc1b,
                            const float* __restrict__ x2hw, const float* __restrict__ x2hb,
                            const float* __restrict__ h2hb,
                            unsigned short* __restrict__ o_wch, unsigned short* __restrict__ o_wcl,
                            float* __restrict__ o_btot) {
    int tid = threadIdx.x;
    int nl  = tid >> 5;
    int f0  = (tid & 31) << 2;
    int n   = blockIdx.x * 8 + nl;
    float a0 = 0.f, a1 = 0.f, a2 = 0.f, a3 = 0.f;
    for (int k = 0; k < 128; k++) {
        float a = x2hw[n * 128 + k];
        const float* fr = fc1w + k * 128 + f0;
        a0 += a * fr[0]; a1 += a * fr[1]; a2 += a * fr[2]; a3 += a * fr[3];
    }
    float vs[4] = {a0, a1, a2, a3};
    for (int j = 0; j < 4; j++) {
        unsigned short h = f2bf(vs[j]);
        o_wch[n * 128 + f0 + j] = h;
        o_wcl[n * 128 + f0 + j] = f2bf(vs[j] - bf2f(h));
    }
    if ((tid & 31) == 0) {
        float s = 0.f;
        for (int k = 0; k < 128; k++) s += x2hw[n * 128 + k] * fc1b[k];
        o_btot[n] = s + x2hb[n] + h2hb[n];
    }
}

// ---------------------------------------------------------------------------
// Persistent RNN: 256 blocks x 512 threads (64 batch-groups x 4 hidden
// slices). Wh slice (128KB) + h hi/lo (32KB) LDS-resident. Exchange h via
// global Hbuf: R9's proven agent-scope atomic protocol, with (a) flags padded
// to one cache line each, (b) Hbuf in writer-lane order => coalesced 512B
// runs per wave on both store and load sides. No inline asm, no XCD
// assumptions.
// ---------------------------------------------------------------------------
__launch_bounds__(512, 1)
__global__ void rnn_kernel(const int* __restrict__ w_x,
                           const unsigned short* __restrict__ w_len,
                           const unsigned short* __restrict__ w_ipd,
                           const unsigned short* __restrict__ w_wh,
                           const unsigned short* __restrict__ w_fc2,
                           const float* __restrict__ w_fc2b,
                           const unsigned short* __restrict__ w_wch,
                           const unsigned short* __restrict__ w_wcl,
                           const float* __restrict__ w_btot,
                           unsigned short* __restrict__ hb,
                           int* __restrict__ F,
                           float* __restrict__ out) {
    extern __shared__ unsigned short smem[];
    unsigned short* sWh = smem;            // 65536 ushorts (128 KB)
    unsigned short* sH  = smem + 65536;    // 16384 ushorts (32 KB)

    const int tid  = threadIdx.x;
    const int wv   = tid >> 6;             // 0..7, owns n-tile wv (16 rows)
    const int ln   = tid & 63;
    const int mcol = ln & 15;
    const int q    = ln >> 4;
    const int b    = blockIdx.x;
    const int g    = (b >> 5) * 8 + (b & 7);
    const int s    = (b >> 3) & 3;
    const int b0   = g * 16;
    ull* hb64 = (ull*)hb;

    // ---- load Wh slice into LDS (swizzled) ----
    for (int it = 0; it < 16; it++) {
        int idx = it * 512 + tid;            // 16B chunk id, 0..8191
        int r = idx >> 6, c = idx & 63;
        uint4 v = *(const uint4*)(w_wh + ((s * SLICE + r) << 9) + (c << 3));
        *(uint4*)&sWh[(r << 9) + (((c ^ (r & 63)) & 63) << 3)] = v;
    }
    // ---- zero h ----
    for (int i = 0; i < 4; i++) {
        uint4 z = {0, 0, 0, 0};
        *(uint4*)&sH[(i * 512 + tid) * 8] = z;
    }
    // ---- persistent Wc fragments + bias ----
    short8 wc_hi[4], wc_lo[4];
#pragma unroll
    for (int kt = 0; kt < 4; kt++) {
        int off = ((s * SLICE + wv * 16 + mcol) * 128) + kt * 32 + q * 8;
        wc_hi[kt] = *(const short8*)(w_wch + off);
        wc_lo[kt] = *(const short8*)(w_wcl + off);
    }
    const float4v bt = *(const float4v*)(w_btot + s * SLICE + wv * 16 + q * 4);

    __syncthreads();

    for (int t = 0; t < T_SZ; t++) {
        // ---- feats B-frags to registers ----
        short8 ff[4];
        {
            int xoff = (b0 + mcol) * 256 + t * 2;
            int i0 = w_x[xoff], i1 = w_x[xoff + 1];
            const unsigned short* lr = w_len + i0 * 64 + q * 8;
            const unsigned short* ir = w_ipd + i1 * 64 + q * 8;
            ff[0] = *(const short8*)lr;  ff[1] = *(const short8*)(lr + 32);
            ff[2] = *(const short8*)ir;  ff[3] = *(const short8*)(ir + 32);
        }
        // ---- h-independent Wc MFMAs (overlap sibling lag) ----
        float4v acc = bt;
#pragma unroll
        for (int kt = 0; kt < 4; kt++) {
            acc = mfma16(wc_hi[kt], ff[kt], acc);
            acc = mfma16(wc_lo[kt], ff[kt], acc);
        }
        // ---- exchange-in: wait siblings' h_t, coalesced copy into sH ----
        if (t >= 1) {
            const int par = t & 1;
            if (tid < 3) {
                int so = (s + 1 + tid) & 3;
                while (__hip_atomic_load(&F[FSLOT(g, so)], __ATOMIC_ACQUIRE,
                                         __HIP_MEMORY_SCOPE_AGENT) < t)
                    __builtin_amdgcn_s_sleep(2);
            }
            __syncthreads();
#pragma unroll
            for (int i = 0; i < 6; i++) {
                int u   = i * 512 + tid;             // 0..3071 (8B units)
                int sp  = (s + 1 + (u >> 10)) & 3;
                int rem = u & 1023;
                int pl  = rem >> 9;
                int wvr = (rem >> 6) & 7;
                int lnr = rem & 63;
                ull v = __hip_atomic_load(hb64 + (HB2(g, par, sp, pl, wvr, lnr) >> 2),
                                          __ATOMIC_RELAXED, __HIP_MEMORY_SCOPE_AGENT);
                int nl = wvr * 16 + (lnr >> 4) * 4;
                union { ull u8; uint2 v2; } cv; cv.u8 = v;
                *(uint2*)&sH[h_addr(pl, lnr & 15, sp * SLICE + nl)] = cv.v2;
            }
        }
        __syncthreads();   // (A) sH complete

        // ---- Wh MFMAs ----
#pragma unroll 4
        for (int kt = 0; kt < 16; kt++) {
            int k = kt * 32 + q * 8;
            short8 bhi = *(const short8*)&sH[h_addr(0, mcol, k)];
            short8 blo = *(const short8*)&sH[h_addr(1, mcol, k)];
            short8 a   = *(const short8*)&sWh[wh_addr(wv * 16 + mcol, k)];
            acc = mfma16(a, bhi, acc);
            acc = mfma16(a, blo, acc);
        }
        __syncthreads();   // (B) all sH reads done

        // ---- tanh -> hi/lo; coalesced export + local update ----
        {
            unsigned short hi4[4], lo4[4];
#pragma unroll
            for (int r = 0; r < 4; r++) {
                float v = fminf(15.f, fmaxf(-15.f, acc[r]));
                float e = __expf(2.0f * v);
                float th = 1.0f - 2.0f / (e + 1.0f);
                hi4[r] = f2bf(th);
                lo4[r] = f2bf(th - bf2f(hi4[r]));
            }
            int nl = wv * 16 + q * 4;
            union { ull u8; uint2 v2; } vh, vl;
            vh.u8 = (ull)hi4[0] | ((ull)hi4[1] << 16) | ((ull)hi4[2] << 32) | ((ull)hi4[3] << 48);
            vl.u8 = (ull)lo4[0] | ((ull)lo4[1] << 16) | ((ull)lo4[2] << 32) | ((ull)lo4[3] << 48);
            const int wpar = (t + 1) & 1;
            __hip_atomic_store(hb64 + (HB2(g, wpar, s, 0, wv, ln) >> 2), vh.u8,
                               __ATOMIC_RELAXED, __HIP_MEMORY_SCOPE_AGENT);
            __hip_atomic_store(hb64 + (HB2(g, wpar, s, 1, wv, ln) >> 2), vl.u8,
                               __ATOMIC_RELAXED, __HIP_MEMORY_SCOPE_AGENT);
            *(uint2*)&sH[h_addr(0, mcol, s * SLICE + nl)] = vh.v2;
            *(uint2*)&sH[h_addr(1, mcol, s * SLICE + nl)] = vl.v2;
        }
        __syncthreads();   // (C) drains all waves' stores (vmcnt(0) pre-barrier)
        if (tid == 0)
            __hip_atomic_store(&F[FSLOT(g, s)], t + 1, __ATOMIC_RELEASE,
                               __HIP_MEMORY_SCOPE_AGENT);
    }

    if (s != 0) return;

    // ---- final exchange (parity 0) + fc2 epilogue on slice-0 blocks ----
    if (tid < 3) {
        int so = 1 + tid;
        while (__hip_atomic_load(&F[FSLOT(g, so)], __ATOMIC_ACQUIRE,
                                 __HIP_MEMORY_SCOPE_AGENT) < T_SZ)
            __builtin_amdgcn_s_sleep(2);
    }
    __syncthreads();
#pragma unroll
    for (int i = 0; i < 6; i++) {
        int u   = i * 512 + tid;
        int sp  = 1 + (u >> 10);
        int rem = u & 1023;
        int pl  = rem >> 9;
        int wvr = (rem >> 6) & 7;
        int lnr = rem & 63;
        ull v = __hip_atomic_load(hb64 + (HB2(g, 0, sp, pl, wvr, lnr) >> 2),
                                  __ATOMIC_RELAXED, __HIP_MEMORY_SCOPE_AGENT);
        int nl = wvr * 16 + (lnr >> 4) * 4;
        union { ull u8; uint2 v2; } cv; cv.u8 = v;
        *(uint2*)&sH[h_addr(pl, lnr & 15, sp * SLICE + nl)] = cv.v2;
    }
    __syncthreads();

    if (wv < 7) {
        int lA = wv * 16 + mcol; if (lA > 99) lA = 99;
        float4v a2 = {0.f, 0.f, 0.f, 0.f};
#pragma unroll 4
        for (int kt = 0; kt < 16; kt++) {
            int k = kt * 32 + q * 8;
            short8 fa  = *(const short8*)(w_fc2 + lA * 512 + k);
            short8 bhi = *(const short8*)&sH[h_addr(0, mcol, k)];
            short8 blo = *(const short8*)&sH[h_addr(1, mcol, k)];
            a2 = mfma16(fa, bhi, a2);
            a2 = mfma16(fa, blo, a2);
        }
#pragma unroll
        for (int r = 0; r < 4; r++) {
            int l = wv * 16 + q * 4 + r;
            if (l < 100) out[(b0 + mcol) * 100 + l] = a2[r] + w_fc2b[l];
        }
    }
}

extern "C" void kernel_launch(void* const* d_in, const int* in_sizes, int n_in,
                              void* d_out, int out_size, void* d_ws, size_t ws_size,
                              hipStream_t stream) {
    unsigned char* base = (unsigned char*)d_ws;
    if (ws_size < (size_t)WS_NEED) {
        void* p = nullptr;
        hipGetSymbolAddress(&p, HIP_SYMBOL(g_blob));
        base = (unsigned char*)p;
    }
    int*            w_x    = (int*)(base + OFF_X);
    unsigned short* w_wh   = (unsigned short*)(base + OFF_WH);
    unsigned short* w_len  = (unsigned short*)(base + OFF_LEN);
    unsigned short* w_ipd  = (unsigned short*)(base + OFF_IPD);
    unsigned short* w_fc2  = (unsigned short*)(base + OFF_FC2);
    unsigned short* w_wch  = (unsigned short*)(base + OFF_WCH);
    unsigned short* w_wcl  = (unsigned short*)(base + OFF_WCL);
    float*          w_btot = (float*)(base + OFF_BTOT);
    float*          w_fc2b = (float*)(base + OFF_FC2B);
    unsigned short* w_hbuf = (unsigned short*)(base + OFF_HBUF);
    int*            w_sync = (int*)(base + OFF_SYNC);

    static bool attr_set = false;
    if (!attr_set) {
        hipFuncSetAttribute((const void*)rnn_kernel,
                            hipFuncAttributeMaxDynamicSharedMemorySize, 163840);
        attr_set = true;
    }

    init_sync_kernel<<<1, 1024, 0, stream>>>(w_sync);
    conv_x_kernel<<<256, 256, 0, stream>>>((const int*)d_in[0], w_x);
    conv_floats_kernel<<<1024, 256, 0, stream>>>(
        (const float*)d_in[1], (const float*)d_in[2], (const float*)d_in[7],
        (const float*)d_in[9], (const float*)d_in[10],
        w_len, w_ipd, w_wh, w_fc2, w_fc2b);
    prep_kernel<<<64, 256, 0, stream>>>(
        (const float*)d_in[3], (const float*)d_in[4], (const float*)d_in[5],
        (const float*)d_in[6], (const float*)d_in[8],
        w_wch, w_wcl, w_btot);
    rnn_kernel<<<256, 512, 163840, stream>>>(
        w_x, w_len, w_ipd, w_wh, w_fc2, w_fc2b, w_wch, w_wcl, w_btot,
        w_hbuf, w_sync, (float*)d_out);
}